// Round 12
// baseline (127.590 us; speedup 1.0000x reference)
//
#include <hip/hip_runtime.h>
#include <math.h>

#define P_TOT 100000
#define BM    32
#define NBLK  3125

// ws float offsets
#define OFF_BIH   0        // 96 frags (6kc x 8w x 2nt) x 1KB, GATE-PERMUTED cols, hi only, exp2-prescaled
#define OFF_BHH   24576    // 32 frags (2kc x 8w x 2nt), gate-permuted, hi only, exp2-prescaled
#define OFF_BA    32768    // 16 frags (2kc x 8ntg), standard cols, hi only (NOT scaled)
#define OFF_BSUM  36864    // 256 (natural order, exp2-prescaled)
#define OFF_CTXP  37120    // 128
#define OFF_MISC  37248    // [0]=safety, [1]=invZ
#define OFF_E     37264    // 100000
#define OFF_PE    137264   // 3125
#define OFF_PAGG  140392   // 3125*64
#define OFF_P2E   340392   // 64
#define OFF_P2AGG 340456   // 256*64
// hi-only bf16 embedding tables: [row][128B] = 32 f32-slots/row
#define OFF_TAB   356864
#define OFF_TU    (OFF_TAB)                 // 100000 rows
#define OFF_TI    (OFF_TAB + 3200000)       // 50000 rows
#define OFF_TR    (OFF_TAB + 4800000)       // 8 rows
#define OFF_TT    (OFF_TAB + 4800256)       // 2 rows
#define WS_FAST_BYTES ((size_t)(OFF_TAB + 4800320) * 4)

// klstm LDS (34944 B):
//  AF2 @0 (24576): [2s][32p]x384B hi-only swizzled A tiles (2-step staging); attn HIDB (16KB) overlays @0
//  AHB @24576 (8192): 2 x [32p]x128B h bf16, double-buffered, swizzled
//  ES  @32768 (128) | PART @32896 (2048)
#define AHB   24576
#define ESO   32768
#define PARTO 32896
#define LDS_BYTES 34944

#define LOG2E  1.442695041f
#define LOG2E2 2.885390082f

typedef short bf16x8 __attribute__((ext_vector_type(8)));
typedef float f32x4  __attribute__((ext_vector_type(4)));

#define MFMA16(a,b,c) __builtin_amdgcn_mfma_f32_16x16x32_bf16((a),(b),(c),0,0,0)

__device__ __forceinline__ unsigned short cvh(float v){
  unsigned int u = __float_as_uint(v);
  return (unsigned short)((u + 0x7fffu + ((u>>16)&1u)) >> 16);
}
__device__ __forceinline__ float fexp2(float x){
#if __has_builtin(__builtin_amdgcn_exp2f)
  return __builtin_amdgcn_exp2f(x);
#else
  return exp2f(x);
#endif
}
__device__ __forceinline__ float frcp(float x){
#if __has_builtin(__builtin_amdgcn_rcpf)
  return __builtin_amdgcn_rcpf(x);
#else
  return 1.f/x;
#endif
}
__device__ __forceinline__ float sigm2(float zp){ return frcp(1.f + fexp2(-zp)); }
__device__ __forceinline__ float tanh2(float zp){
  float e2 = fexp2(zp);
  return (e2 - 1.f) * frcp(e2 + 1.f);
}
__device__ __forceinline__ float tanh_c(float c){ return tanh2(c * LOG2E2); }

// ---------------------------------------------------------------- prep (weights)
__global__ __launch_bounds__(256) void kprep(
    const int* __restrict__ user_idx, const int* __restrict__ item_idx,
    const float* __restrict__ user_emb, const float* __restrict__ item_emb,
    const float* __restrict__ W_ih, const float* __restrict__ W_hh,
    const float* __restrict__ b_ih, const float* __restrict__ b_hh,
    const float* __restrict__ att_W1, const float* __restrict__ att_b1,
    const float* __restrict__ saf_W1, const float* __restrict__ saf_b1,
    const float* __restrict__ saf_W2, const float* __restrict__ saf_b2,
    float* __restrict__ ws)
{
  const int t = threadIdx.x;
  for (int fb = blockIdx.x; fb < 144; fb += gridDim.x){
    const float* src; int base, rowlen, kc; bool perm; int w=0, nt=0, ntg=0;
    if (fb < 96){ kc = fb>>4; int rem = fb&15; w = rem>>1; nt = rem&1; perm = true;
                  base = OFF_BIH + fb*256; src = W_ih; rowlen = 192; }
    else if (fb < 128){ int f2 = fb-96; kc = f2>>4; int rem = f2&15; w = rem>>1; nt = rem&1; perm = true;
                  base = OFF_BHH + f2*256; src = W_hh; rowlen = 64; }
    else { int f3 = fb-128; kc = f3>>3; ntg = f3&7; perm = false;
                  base = OFF_BA + f3*256; src = att_W1; rowlen = 192; }
    unsigned short* dst = (unsigned short*)(ws + base);
    for (int e = t; e < 512; e += 256){
      int l = e>>3, j = e&7;
      int c = l&15;
      int n = perm ? (nt*2 + (c>>3))*64 + w*8 + (c&7)
                   : ntg*16 + c;
      int k = kc*32 + (l>>4)*8 + j;
      float v = src[n*rowlen + k];
      if (perm) v *= ((n>>6)==2 ? LOG2E2 : LOG2E);   // exp2 pre-scale per gate
      dst[e] = cvh(v);
    }
  }
  if (blockIdx.x == 0){
    __shared__ float ctx[128];
    if (t < 256) ws[OFF_BSUM+t] = (b_ih[t] + b_hh[t]) * ((t>>6)==2 ? LOG2E2 : LOG2E);
    if (t < 64){
      ctx[t]    = user_emb[user_idx[0]*64 + t];
      ctx[64+t] = item_emb[item_idx[0]*64 + t];
    }
    __syncthreads();
    if (t < 128){
      float s = att_b1[t];
      for (int k=0;k<128;++k) s = fmaf(att_W1[t*192 + 64 + k], ctx[k], s);
      ws[OFF_CTXP + t] = s;
    }
    if (t < 32){
      float s = saf_b1[t];
      for (int k=0;k<128;++k) s = fmaf(saf_W1[t*128+k], ctx[k], s);
      s = fmaxf(s, 0.f);
      float v = s * saf_W2[t];
      v += __shfl_xor(v,1); v += __shfl_xor(v,2); v += __shfl_xor(v,4);
      v += __shfl_xor(v,8); v += __shfl_xor(v,16);
      if (t==0) ws[OFF_MISC+0] = 1.f/(1.f+expf(-(v + saf_b2[0])));
    }
  }
}

// ---------------------------------------------------------------- table conversion (hi-only)
__global__ __launch_bounds__(256) void kconv(
    const float* __restrict__ user_emb, const float* __restrict__ item_emb,
    const float* __restrict__ relation_emb, const float* __restrict__ node_type_emb,
    float* __restrict__ ws)
{
  const int gid = blockIdx.x*256 + threadIdx.x;
  const int row = gid >> 3, seg = gid & 7;
  if (row >= 150010) return;
  const float* src; int dstoff;
  if (row < 100000){ src = user_emb + row*64;             dstoff = OFF_TU + row*32; }
  else if (row < 150000){ src = item_emb + (row-100000)*64; dstoff = OFF_TI + (row-100000)*32; }
  else if (row < 150008){ src = relation_emb + (row-150000)*64; dstoff = OFF_TR + (row-150000)*32; }
  else { src = node_type_emb + (row-150008)*64;           dstoff = OFF_TT + (row-150008)*32; }
  float4 v0 = ((const float4*)(src + seg*8))[0];
  float4 v1 = ((const float4*)(src + seg*8))[1];
  uint4 hq;
  hq.x = (unsigned)cvh(v0.x) | ((unsigned)cvh(v0.y)<<16);
  hq.y = (unsigned)cvh(v0.z) | ((unsigned)cvh(v0.w)<<16);
  hq.z = (unsigned)cvh(v1.x) | ((unsigned)cvh(v1.y)<<16);
  hq.w = (unsigned)cvh(v1.z) | ((unsigned)cvh(v1.w)<<16);
  *(uint4*)((char*)(ws + dstoff) + seg*16) = hq;
}

// ---------------------------------------------------------------- main: LSTM + attention (BM=32, per-step acc)
template<int PRE>
__global__ __launch_bounds__(512,4) void klstm(
    const int* __restrict__ node_ids, const int* __restrict__ node_types,
    const int* __restrict__ rel_idx,
    const float* __restrict__ user_emb, const float* __restrict__ item_emb,
    const float* __restrict__ relation_emb, const float* __restrict__ node_type_emb,
    const float* __restrict__ att_W2, const float* __restrict__ att_b2,
    float* __restrict__ ws)
{
  __shared__ __align__(16) unsigned char smem[LDS_BYTES];
  const int t   = threadIdx.x;
  const int l   = t & 63, wid = t >> 6;
  const int ln  = l & 15, lk = l >> 4;
  const int bid = blockIdx.x, p0 = bid*BM;
  const bf16x8* Bih = (const bf16x8*)(ws + OFF_BIH);
  const bf16x8* Bhh = (const bf16x8*)(ws + OFF_BHH);
  const bf16x8* Bab = (const bf16x8*)(ws + OFF_BA);
  const int swA = (ln&7)<<4;
  const int c8 = t&7, rr = t>>3;

  // stage steps {half*2, half*2+1} into AF2 slots {0,1}: 192 tasks, 3/thread-group
  auto gather_half = [&](int half){
    #pragma unroll
    for (int i=0;i<3;++i){
      int task = rr + i*64;                 // [0,192)
      int src = task>>6, s2 = (task>>5)&1, p = task&31;
      int gi = (p0+p)*4 + half*2 + s2;
      int dsta = (s2*32 + p)*384 + ((src*128 + c8*16) ^ ((p&7)<<4));
      if (PRE){
        const char* rp;
        if (src==0){ int nid = node_ids[gi];
                     rp = (const char*)(ws + (node_types[gi]==0 ? OFF_TU + nid*32 : OFF_TI + nid*32)); }
        else if (src==1){ rp = (const char*)(ws + OFF_TT + node_types[gi]*32); }
        else { rp = (const char*)(ws + OFF_TR + rel_idx[gi]*32); }
        *(uint4*)(smem + dsta) = *(const uint4*)(rp + c8*16);
      } else {
        const float* sp;
        if (src==0){ int nid = node_ids[gi]; sp = (node_types[gi]==0 ? user_emb : item_emb) + nid*64; }
        else if (src==1){ sp = node_type_emb + node_types[gi]*64; }
        else { sp = relation_emb + rel_idx[gi]*64; }
        float4 v0 = ((const float4*)sp)[c8*2];
        float4 v1 = ((const float4*)sp)[c8*2+1];
        uint4 hq;
        hq.x = (unsigned)cvh(v0.x) | ((unsigned)cvh(v0.y)<<16);
        hq.y = (unsigned)cvh(v0.z) | ((unsigned)cvh(v0.w)<<16);
        hq.z = (unsigned)cvh(v1.x) | ((unsigned)cvh(v1.y)<<16);
        hq.w = (unsigned)cvh(v1.z) | ((unsigned)cvh(v1.w)<<16);
        *(uint4*)(smem + dsta) = hq;
      }
    }
  };

  const float bv0 = ws[OFF_BSUM + ((ln>>3))*64   + wid*8 + (ln&7)];
  const float bv1 = ws[OFF_BSUM + (2+(ln>>3))*64 + wid*8 + (ln&7)];
  const int hi8 = ln>>3;
  const int dd  = wid*8 + (ln&7);
  float c0[2] = {0.f,0.f}, c1[2] = {0.f,0.f};

  gather_half(0);
  __syncthreads();

  #pragma unroll
  for (int s=0;s<4;++s){
    if (s == 2){                      // slots 0,1 fully consumed (end-of-s1 barrier passed)
      gather_half(1);
      __syncthreads();
    }
    const int slot = s&1;
    f32x4 acc[2][2];                  // [ptile][nt] — 16 AGPRs live
    #pragma unroll
    for (int pt=0;pt<2;++pt){
      acc[pt][0] = (f32x4){bv0,bv0,bv0,bv0};
      acc[pt][1] = (f32x4){bv1,bv1,bv1,bv1};
    }
    // input GEMM: K=192
    #pragma unroll 2
    for (int kc=0;kc<6;++kc){
      bf16x8 bh0 = Bih[(unsigned)((kc*16 + wid*2+0)*64 + l)];
      bf16x8 bh1 = Bih[(unsigned)((kc*16 + wid*2+1)*64 + l)];
      #pragma unroll
      for (int pt=0;pt<2;++pt){
        bf16x8 ah = *(const bf16x8*)(smem + (slot*32 + pt*16 + ln)*384 + ((kc*64 + lk*16) ^ swA));
        acc[pt][0] = MFMA16(ah, bh0, acc[pt][0]);
        acc[pt][1] = MFMA16(ah, bh1, acc[pt][1]);
      }
    }
    // recurrent GEMM: K=64
    if (s > 0){
      const int rb = AHB + (s&1)*4096;
      #pragma unroll
      for (int kc=0;kc<2;++kc){
        bf16x8 bh0 = Bhh[(unsigned)((kc*16 + wid*2+0)*64 + l)];
        bf16x8 bh1 = Bhh[(unsigned)((kc*16 + wid*2+1)*64 + l)];
        #pragma unroll
        for (int pt=0;pt<2;++pt){
          bf16x8 ah = *(const bf16x8*)(smem + rb + (pt*16 + ln)*128 + ((kc*64 + lk*16) ^ swA));
          acc[pt][0] = MFMA16(ah, bh0, acc[pt][0]);
          acc[pt][1] = MFMA16(ah, bh1, acc[pt][1]);
        }
      }
    }
    // gates from registers (partner exchange via shfl_xor 8)
    const int wb = AHB + ((s&1)^1)*4096;
    #pragma unroll
    for (int pt=0;pt<2;++pt){
      float a00 = acc[pt][0][0], a01 = acc[pt][0][1], a02 = acc[pt][0][2], a03 = acc[pt][0][3];
      float a10 = acc[pt][1][0], a11 = acc[pt][1][1], a12 = acc[pt][1][2], a13 = acc[pt][1][3];
      float p00 = __shfl_xor(a00,8), p01 = __shfl_xor(a01,8);
      float p02 = __shfl_xor(a02,8), p03 = __shfl_xor(a03,8);
      float p10 = __shfl_xor(a10,8), p11 = __shfl_xor(a11,8);
      float p12 = __shfl_xor(a12,8), p13 = __shfl_xor(a13,8);
      float vi0 = hi8 ? p02 : a00;  float vf0 = hi8 ? a02 : p00;
      float vg0 = hi8 ? p12 : a10;  float vo0 = hi8 ? a12 : p10;
      float vi1 = hi8 ? p03 : a01;  float vf1 = hi8 ? a03 : p01;
      float vg1 = hi8 ? p13 : a11;  float vo1 = hi8 ? a13 : p11;
      float i0 = sigm2(vi0), f0 = sigm2(vf0), g0 = tanh2(vg0), o0 = sigm2(vo0);
      float i1 = sigm2(vi1), f1 = sigm2(vf1), g1 = tanh2(vg1), o1 = sigm2(vo1);
      c0[pt] = fmaf(f0, c0[pt], i0*g0);
      c1[pt] = fmaf(f1, c1[pt], i1*g1);
      float h0 = o0 * tanh_c(c0[pt]);
      float h1 = o1 * tanh_c(c1[pt]);
      int pth0 = pt*16 + lk*4 + hi8*2, pth1 = pth0 + 1;
      *(unsigned short*)(smem + wb + pth0*128 + ((dd*2) ^ ((pth0&7)<<4))) = cvh(h0);
      *(unsigned short*)(smem + wb + pth1*128 + ((dd*2) ^ ((pth1&7)<<4))) = cvh(h1);
    }
    __syncthreads();
  }
  // h_n now in AHB buf0 (bf16, swizzled)

  // ---- attention hidden: relu(h @ BA + ctxp) -> HIDB [32p][128] f32 overlays AF2@0
  {
    const int pt = wid>>2, wg = wid&3;
    f32x4 acc2[2];
    #pragma unroll
    for (int nt=0;nt<2;++nt){
      float cv = ws[OFF_CTXP + wg*32 + nt*16 + ln];
      acc2[nt] = (f32x4){cv,cv,cv,cv};
    }
    #pragma unroll
    for (int kc=0;kc<2;++kc){
      bf16x8 ah = *(const bf16x8*)(smem + AHB + (pt*16 + ln)*128 + ((kc*64 + lk*16) ^ swA));
      bf16x8 bh0 = Bab[(unsigned)((kc*8 + wg*2+0)*64 + l)];
      bf16x8 bh1 = Bab[(unsigned)((kc*8 + wg*2+1)*64 + l)];
      acc2[0] = MFMA16(ah, bh0, acc2[0]);
      acc2[1] = MFMA16(ah, bh1, acc2[1]);
    }
    __syncthreads();   // AF2 reads long done; safe to overlay
    #pragma unroll
    for (int nt=0;nt<2;++nt)
      #pragma unroll
      for (int r=0;r<4;++r)
        *(float*)(smem + (pt*16 + lk*4+r)*512 + (wg*32 + nt*16 + ln)*4) = fmaxf(acc2[nt][r], 0.f);
  }
  __syncthreads();
  // ---- score = hidden . att_W2 + b2 ; e = exp(score)
  {
    int p = t>>4, seg = t&15;
    float4 a0 = *(const float4*)(smem + p*512 + seg*32);
    float4 a1 = *(const float4*)(smem + p*512 + seg*32 + 16);
    float4 w0 = *(const float4*)(att_W2 + seg*8);
    float4 w1 = *(const float4*)(att_W2 + seg*8 + 4);
    float sc = a0.x*w0.x; sc = fmaf(a0.y,w0.y,sc); sc = fmaf(a0.z,w0.z,sc); sc = fmaf(a0.w,w0.w,sc);
    sc = fmaf(a1.x,w1.x,sc); sc = fmaf(a1.y,w1.y,sc); sc = fmaf(a1.z,w1.z,sc); sc = fmaf(a1.w,w1.w,sc);
    sc += __shfl_xor(sc,1); sc += __shfl_xor(sc,2); sc += __shfl_xor(sc,4); sc += __shfl_xor(sc,8);
    if (seg == 0){
      float e = __expf(sc + att_b2[0]);
      *(float*)(smem + ESO + p*4) = e;
      ws[OFF_E + p0 + p] = e;
    }
  }
  __syncthreads();
  // ---- partial sums: sum(e), sum(e*h)  (h as bf16 from AHB buf0)
  {
    int pg = t>>6, d = t&63;
    const float* es = (const float*)(smem + ESO);
    float a = 0.f;
    #pragma unroll
    for (int pi=0;pi<4;++pi){
      int p = pg*4 + pi;
      unsigned short hu = *(const unsigned short*)(smem + AHB + p*128 + ((d*2) ^ ((p&7)<<4)));
      a = fmaf(es[p], __uint_as_float((unsigned)hu << 16), a);
    }
    *(float*)(smem + PARTO + (pg*64+d)*4) = a;
  }
  __syncthreads();
  if (t < 64){
    const float* part = (const float*)(smem + PARTO);
    float a = 0.f;
    #pragma unroll
    for (int pg=0;pg<8;++pg) a += part[pg*64 + t];
    ws[OFF_PAGG + bid*64 + t] = a;
  }
  if (t < 32){
    float e2 = *(const float*)(smem + ESO + t*4);
    e2 += __shfl_xor(e2,1); e2 += __shfl_xor(e2,2);
    e2 += __shfl_xor(e2,4); e2 += __shfl_xor(e2,8); e2 += __shfl_xor(e2,16);
    if (t==0) ws[OFF_PE + bid] = e2;
  }
}

// ---------------------------------------------------------------- reduce stage A: 64 blocks
__global__ __launch_bounds__(256) void kredA(float* __restrict__ ws)
{
  const float* p_e   = ws + OFF_PE;
  const float* p_agg = ws + OFF_PAGG;
  __shared__ float red[256];
  const int b = blockIdx.x, t = threadIdx.x;
  const int s = b*4 + (t>>6), d = t&63;
  float a = 0.f;
  for (int row = s; row < NBLK; row += 256) a += p_agg[row*64 + d];
  ws[OFF_P2AGG + s*64 + d] = a;
  float pe = 0.f;
  {
    int i = b*49 + t;
    if (t < 49 && i < NBLK) pe = p_e[i];
  }
  pe += __shfl_xor(pe,1); pe += __shfl_xor(pe,2); pe += __shfl_xor(pe,4);
  pe += __shfl_xor(pe,8); pe += __shfl_xor(pe,16); pe += __shfl_xor(pe,32);
  if ((t&63)==0) red[t>>6] = pe;
  __syncthreads();
  if (t==0) ws[OFF_P2E + b] = red[0]+red[1]+red[2]+red[3];
}

// ---------------------------------------------------------------- reduce stage B + heads: 1 block
__global__ __launch_bounds__(256) void kredB(
    const float* __restrict__ val_W1, const float* __restrict__ val_b1,
    const float* __restrict__ val_W2, const float* __restrict__ val_b2,
    float* __restrict__ ws, float* __restrict__ d_out)
{
  __shared__ float aggL[64];
  __shared__ float red[256];
  __shared__ float Zs;
  const int t = threadIdx.x;
  {
    float pe = (t < 64) ? ws[OFF_P2E + t] : 0.f;
    pe += __shfl_xor(pe,1); pe += __shfl_xor(pe,2); pe += __shfl_xor(pe,4);
    pe += __shfl_xor(pe,8); pe += __shfl_xor(pe,16); pe += __shfl_xor(pe,32);
    if (t==0){ Zs = pe; ws[OFF_MISC+1] = 1.f/pe; }
  }
  {
    int d = t&63, q = t>>6;
    float a = 0.f;
    #pragma unroll 4
    for (int s2=q; s2<256; s2+=4) a += ws[OFF_P2AGG + s2*64 + d];
    red[t] = a;
  }
  __syncthreads();
  if (t < 64) aggL[t] = (red[t] + red[64+t] + red[128+t] + red[192+t]) / Zs;
  __syncthreads();
  if (t < 32){
    float hv = val_b1[t];
    for (int k=0;k<64;++k) hv = fmaf(aggL[k], val_W1[t*64+k], hv);
    hv = fmaxf(hv, 0.f);
    float v = hv * val_W2[t];
    v += __shfl_xor(v,1); v += __shfl_xor(v,2); v += __shfl_xor(v,4);
    v += __shfl_xor(v,8); v += __shfl_xor(v,16);
    // q_value = value + (advantage - mean(advantage)) == value (advantage is [1])
    if (t==0) d_out[0] = (v + val_b2[0]) * ws[OFF_MISC+0];
  }
}

// ---------------------------------------------------------------- att weights out
__global__ __launch_bounds__(256) void kweights(
    const float* __restrict__ ws, float* __restrict__ d_out)
{
  int p = blockIdx.x*256 + threadIdx.x;
  if (p < P_TOT) d_out[1+p] = ws[OFF_E + p] * ws[OFF_MISC+1];
}

// ---------------------------------------------------------------- launch
extern "C" void kernel_launch(void* const* d_in, const int* in_sizes, int n_in,
                              void* d_out, int out_size, void* d_ws, size_t ws_size,
                              hipStream_t stream) {
  const int*   user_idx   = (const int*)  d_in[0];
  const int*   item_idx   = (const int*)  d_in[1];
  const int*   node_ids   = (const int*)  d_in[2];
  const int*   node_types = (const int*)  d_in[3];
  const int*   rel_idx    = (const int*)  d_in[4];
  const float* user_emb   = (const float*)d_in[5];
  const float* item_emb   = (const float*)d_in[6];
  const float* rel_emb    = (const float*)d_in[7];
  const float* ntype_emb  = (const float*)d_in[8];
  const float* W_ih       = (const float*)d_in[9];
  const float* W_hh       = (const float*)d_in[10];
  const float* b_ih       = (const float*)d_in[11];
  const float* b_hh       = (const float*)d_in[12];
  const float* att_W1     = (const float*)d_in[13];
  const float* att_b1     = (const float*)d_in[14];
  const float* att_W2     = (const float*)d_in[15];
  const float* att_b2     = (const float*)d_in[16];
  const float* val_W1     = (const float*)d_in[17];
  const float* val_b1     = (const float*)d_in[18];
  const float* val_W2     = (const float*)d_in[19];
  const float* val_b2     = (const float*)d_in[20];
  const float* saf_W1     = (const float*)d_in[25];
  const float* saf_b1     = (const float*)d_in[26];
  const float* saf_W2     = (const float*)d_in[27];
  const float* saf_b2     = (const float*)d_in[28];
  float* ws  = (float*)d_ws;
  float* out = (float*)d_out;

  const bool fast = (ws_size >= WS_FAST_BYTES);

  hipLaunchKernelGGL(kprep, dim3(64), dim3(256), 0, stream,
                     user_idx, item_idx, user_emb, item_emb,
                     W_ih, W_hh, b_ih, b_hh, att_W1, att_b1,
                     saf_W1, saf_b1, saf_W2, saf_b2, ws);
  if (fast){
    hipLaunchKernelGGL(kconv, dim3((150010*8+255)/256), dim3(256), 0, stream,
                       user_emb, item_emb, rel_emb, ntype_emb, ws);
    hipLaunchKernelGGL(klstm<1>, dim3(NBLK), dim3(512), 0, stream,
                       node_ids, node_types, rel_idx,
                       user_emb, item_emb, rel_emb, ntype_emb,
                       att_W2, att_b2, ws);
  } else {
    hipLaunchKernelGGL(klstm<0>, dim3(NBLK), dim3(512), 0, stream,
                       node_ids, node_types, rel_idx,
                       user_emb, item_emb, rel_emb, ntype_emb,
                       att_W2, att_b2, ws);
  }
  hipLaunchKernelGGL(kredA, dim3(64), dim3(256), 0, stream, ws);
  hipLaunchKernelGGL(kredB, dim3(1), dim3(256), 0, stream,
                     val_W1, val_b1, val_W2, val_b2, ws, out);
  hipLaunchKernelGGL(kweights, dim3((P_TOT+255)/256), dim3(256), 0, stream,
                     ws, out);
}

// Round 13
// 114.290 us; speedup vs baseline: 1.1164x; 1.1164x over previous
//
#include <hip/hip_runtime.h>
#include <math.h>

#define P_TOT 100000
#define BM    32
#define NBLK  3125

// ws float offsets
#define OFF_BIH   0        // 96 frags (6kc x 8w x 2nt) x 1KB, GATE-PERMUTED cols, hi only, exp2-prescaled
#define OFF_BHH   24576    // 32 frags (2kc x 8w x 2nt), gate-permuted, hi only, exp2-prescaled
#define OFF_BA    32768    // 16 frags (2kc x 8ntg), standard cols, hi only (NOT scaled)
#define OFF_BSUM  36864    // 256 (natural order, exp2-prescaled)
#define OFF_CTXP  37120    // 128
#define OFF_MISC  37248    // [0]=safety, [1]=invZ
#define OFF_E     37264    // 100000
#define OFF_PE    137264   // 3125
#define OFF_PAGG  140392   // 3125*64
#define OFF_P2E   340392   // 64
#define OFF_P2AGG 340456   // 256*64
// hi-only bf16 embedding tables: [row][128B] = 32 f32-slots/row
#define OFF_TAB   356864
#define OFF_TU    (OFF_TAB)                 // 100000 rows
#define OFF_TI    (OFF_TAB + 3200000)       // 50000 rows
#define OFF_TR    (OFF_TAB + 4800000)       // 8 rows
#define OFF_TT    (OFF_TAB + 4800256)       // 2 rows
#define WS_FAST_BYTES ((size_t)(OFF_TAB + 4800320) * 4)

// klstm LDS (59520 B) — r11 layout
#define AHB   49152
#define ESO   57344
#define PARTO 57472
#define LDS_BYTES 59520

#define CONV_BLOCKS 4688   // ceil(150010*8/256)
#define PREP_BLOCKS 64

#define LOG2E  1.442695041f
#define LOG2E2 2.885390082f

typedef short bf16x8 __attribute__((ext_vector_type(8)));
typedef float f32x4  __attribute__((ext_vector_type(4)));

#define MFMA16(a,b,c) __builtin_amdgcn_mfma_f32_16x16x32_bf16((a),(b),(c),0,0,0)

__device__ __forceinline__ unsigned short cvh(float v){
  unsigned int u = __float_as_uint(v);
  return (unsigned short)((u + 0x7fffu + ((u>>16)&1u)) >> 16);
}
__device__ __forceinline__ float fexp2(float x){
#if __has_builtin(__builtin_amdgcn_exp2f)
  return __builtin_amdgcn_exp2f(x);
#else
  return exp2f(x);
#endif
}
__device__ __forceinline__ float frcp(float x){
#if __has_builtin(__builtin_amdgcn_rcpf)
  return __builtin_amdgcn_rcpf(x);
#else
  return 1.f/x;
#endif
}
__device__ __forceinline__ float sigm2(float zp){ return frcp(1.f + fexp2(-zp)); }
__device__ __forceinline__ float tanh2(float zp){
  float e2 = fexp2(zp);
  return (e2 - 1.f) * frcp(e2 + 1.f);
}
__device__ __forceinline__ float tanh_c(float c){ return tanh2(c * LOG2E2); }

// ---------------------------------------------------------------- merged prep + table conversion
// last PREP_BLOCKS blocks do weight prep; preceding blocks (if any) do table conv
__global__ __launch_bounds__(256) void kprepconv(
    const int* __restrict__ user_idx, const int* __restrict__ item_idx,
    const float* __restrict__ user_emb, const float* __restrict__ item_emb,
    const float* __restrict__ relation_emb, const float* __restrict__ node_type_emb,
    const float* __restrict__ W_ih, const float* __restrict__ W_hh,
    const float* __restrict__ b_ih, const float* __restrict__ b_hh,
    const float* __restrict__ att_W1, const float* __restrict__ att_b1,
    const float* __restrict__ saf_W1, const float* __restrict__ saf_b1,
    const float* __restrict__ saf_W2, const float* __restrict__ saf_b2,
    float* __restrict__ ws)
{
  const int t = threadIdx.x;
  const int prep0 = (int)gridDim.x - PREP_BLOCKS;
  if ((int)blockIdx.x < prep0){
    // ---- table conversion (hi-only bf16)
    const int gid = blockIdx.x*256 + t;
    const int row = gid >> 3, seg = gid & 7;
    if (row >= 150010) return;
    const float* src; int dstoff;
    if (row < 100000){ src = user_emb + row*64;             dstoff = OFF_TU + row*32; }
    else if (row < 150000){ src = item_emb + (row-100000)*64; dstoff = OFF_TI + (row-100000)*32; }
    else if (row < 150008){ src = relation_emb + (row-150000)*64; dstoff = OFF_TR + (row-150000)*32; }
    else { src = node_type_emb + (row-150008)*64;           dstoff = OFF_TT + (row-150008)*32; }
    float4 v0 = ((const float4*)(src + seg*8))[0];
    float4 v1 = ((const float4*)(src + seg*8))[1];
    uint4 hq;
    hq.x = (unsigned)cvh(v0.x) | ((unsigned)cvh(v0.y)<<16);
    hq.y = (unsigned)cvh(v0.z) | ((unsigned)cvh(v0.w)<<16);
    hq.z = (unsigned)cvh(v1.x) | ((unsigned)cvh(v1.y)<<16);
    hq.w = (unsigned)cvh(v1.z) | ((unsigned)cvh(v1.w)<<16);
    *(uint4*)((char*)(ws + dstoff) + seg*16) = hq;
    return;
  }
  // ---- weight prep
  const int pb = (int)blockIdx.x - prep0;
  for (int fb = pb; fb < 144; fb += PREP_BLOCKS){
    const float* src; int base, rowlen, kc; bool perm; int w=0, nt=0, ntg=0;
    if (fb < 96){ kc = fb>>4; int rem = fb&15; w = rem>>1; nt = rem&1; perm = true;
                  base = OFF_BIH + fb*256; src = W_ih; rowlen = 192; }
    else if (fb < 128){ int f2 = fb-96; kc = f2>>4; int rem = f2&15; w = rem>>1; nt = rem&1; perm = true;
                  base = OFF_BHH + f2*256; src = W_hh; rowlen = 64; }
    else { int f3 = fb-128; kc = f3>>3; ntg = f3&7; perm = false;
                  base = OFF_BA + f3*256; src = att_W1; rowlen = 192; }
    unsigned short* dst = (unsigned short*)(ws + base);
    for (int e = t; e < 512; e += 256){
      int l = e>>3, j = e&7;
      int c = l&15;
      int n = perm ? (nt*2 + (c>>3))*64 + w*8 + (c&7)
                   : ntg*16 + c;
      int k = kc*32 + (l>>4)*8 + j;
      float v = src[n*rowlen + k];
      if (perm) v *= ((n>>6)==2 ? LOG2E2 : LOG2E);   // exp2 pre-scale per gate
      dst[e] = cvh(v);
    }
  }
  if (pb == 0){
    __shared__ float ctx[128];
    if (t < 256) ws[OFF_BSUM+t] = (b_ih[t] + b_hh[t]) * ((t>>6)==2 ? LOG2E2 : LOG2E);
    if (t < 64){
      ctx[t]    = user_emb[user_idx[0]*64 + t];
      ctx[64+t] = item_emb[item_idx[0]*64 + t];
    }
    __syncthreads();
    if (t < 128){
      float s = att_b1[t];
      for (int k=0;k<128;++k) s = fmaf(att_W1[t*192 + 64 + k], ctx[k], s);
      ws[OFF_CTXP + t] = s;
    }
    if (t < 32){
      float s = saf_b1[t];
      for (int k=0;k<128;++k) s = fmaf(saf_W1[t*128+k], ctx[k], s);
      s = fmaxf(s, 0.f);
      float v = s * saf_W2[t];
      v += __shfl_xor(v,1); v += __shfl_xor(v,2); v += __shfl_xor(v,4);
      v += __shfl_xor(v,8); v += __shfl_xor(v,16);
      if (t==0) ws[OFF_MISC+0] = 1.f/(1.f+expf(-(v + saf_b2[0])));
    }
  }
}

// ---------------------------------------------------------------- main: LSTM + attention (r11 kernel, unchanged)
template<int PRE>
__global__ __launch_bounds__(512,4) void klstm(
    const int* __restrict__ node_ids, const int* __restrict__ node_types,
    const int* __restrict__ rel_idx,
    const float* __restrict__ user_emb, const float* __restrict__ item_emb,
    const float* __restrict__ relation_emb, const float* __restrict__ node_type_emb,
    const float* __restrict__ att_W2, const float* __restrict__ att_b2,
    float* __restrict__ ws)
{
  __shared__ __align__(16) unsigned char smem[LDS_BYTES];
  const int t   = threadIdx.x;
  const int l   = t & 63, wid = t >> 6;
  const int ln  = l & 15, lk = l >> 4;
  const int bid = blockIdx.x, p0 = bid*BM;
  const bf16x8* Bih = (const bf16x8*)(ws + OFF_BIH);
  const bf16x8* Bhh = (const bf16x8*)(ws + OFF_BHH);
  const bf16x8* Bab = (const bf16x8*)(ws + OFF_BA);
  const int swA = (ln&7)<<4;

  // ---- gather feats (4 steps x 3 srcs x 32 paths, hi only): 6 tasks/thread
  {
    const int c8 = t&7, rr = t>>3;
    #pragma unroll
    for (int i=0;i<6;++i){
      int task = rr + i*64;                 // [0,384)
      int src = task>>7, s = (task>>5)&3, p = task&31;
      int gi = (p0+p)*4 + s;
      int dsta = (s*32 + p)*384 + ((src*128 + c8*16) ^ ((p&7)<<4));
      if (PRE){
        const char* rp;
        if (src==0){ int nid = node_ids[gi];
                     rp = (const char*)(ws + (node_types[gi]==0 ? OFF_TU + nid*32 : OFF_TI + nid*32)); }
        else if (src==1){ rp = (const char*)(ws + OFF_TT + node_types[gi]*32); }
        else { rp = (const char*)(ws + OFF_TR + rel_idx[gi]*32); }
        *(uint4*)(smem + dsta) = *(const uint4*)(rp + c8*16);
      } else {
        const float* sp;
        if (src==0){ int nid = node_ids[gi]; sp = (node_types[gi]==0 ? user_emb : item_emb) + nid*64; }
        else if (src==1){ sp = node_type_emb + node_types[gi]*64; }
        else { sp = relation_emb + rel_idx[gi]*64; }
        float4 v0 = ((const float4*)sp)[c8*2];
        float4 v1 = ((const float4*)sp)[c8*2+1];
        uint4 hq;
        hq.x = (unsigned)cvh(v0.x) | ((unsigned)cvh(v0.y)<<16);
        hq.y = (unsigned)cvh(v0.z) | ((unsigned)cvh(v0.w)<<16);
        hq.z = (unsigned)cvh(v1.x) | ((unsigned)cvh(v1.y)<<16);
        hq.w = (unsigned)cvh(v1.z) | ((unsigned)cvh(v1.w)<<16);
        *(uint4*)(smem + dsta) = hq;
      }
    }
  }
  // ---- acc init with bias (permuted cols)
  f32x4 acc[4][2][2];     // [step][ptile][nt]
  {
    float bv0 = ws[OFF_BSUM + ((ln>>3))*64   + wid*8 + (ln&7)];
    float bv1 = ws[OFF_BSUM + (2+(ln>>3))*64 + wid*8 + (ln&7)];
    #pragma unroll
    for (int s=0;s<4;++s)
      #pragma unroll
      for (int pt=0;pt<2;++pt){
        acc[s][pt][0] = (f32x4){bv0,bv0,bv0,bv0};
        acc[s][pt][1] = (f32x4){bv1,bv1,bv1,bv1};
      }
  }
  __syncthreads();

  // ---- phase 1: Zfeat all 4 steps x 2 ptiles (K=192)
  #pragma unroll 2
  for (int kc=0;kc<6;++kc){
    bf16x8 bh0 = Bih[(unsigned)((kc*16 + wid*2+0)*64 + l)];
    bf16x8 bh1 = Bih[(unsigned)((kc*16 + wid*2+1)*64 + l)];
    #pragma unroll
    for (int s=0;s<4;++s)
      #pragma unroll
      for (int pt=0;pt<2;++pt){
        bf16x8 ah = *(const bf16x8*)(smem + (s*32 + pt*16 + ln)*384 + ((kc*64 + lk*16) ^ swA));
        acc[s][pt][0] = MFMA16(ah, bh0, acc[s][pt][0]);
        acc[s][pt][1] = MFMA16(ah, bh1, acc[s][pt][1]);
      }
  }

  // ---- phase 2: recurrence, gates from registers (shfl_xor 8)
  const int hi8 = ln>>3;
  const int dd  = wid*8 + (ln&7);
  float c0[2] = {0.f,0.f}, c1[2] = {0.f,0.f};
  #pragma unroll
  for (int s=0;s<4;++s){
    if (s > 0){
      const int rb = AHB + (s&1)*4096;
      #pragma unroll
      for (int kc=0;kc<2;++kc){
        bf16x8 bh0 = Bhh[(unsigned)((kc*16 + wid*2+0)*64 + l)];
        bf16x8 bh1 = Bhh[(unsigned)((kc*16 + wid*2+1)*64 + l)];
        #pragma unroll
        for (int pt=0;pt<2;++pt){
          bf16x8 ah = *(const bf16x8*)(smem + rb + (pt*16 + ln)*128 + ((kc*64 + lk*16) ^ swA));
          acc[s][pt][0] = MFMA16(ah, bh0, acc[s][pt][0]);
          acc[s][pt][1] = MFMA16(ah, bh1, acc[s][pt][1]);
        }
      }
    }
    const int wb = AHB + ((s&1)^1)*4096;
    #pragma unroll
    for (int pt=0;pt<2;++pt){
      float a00 = acc[s][pt][0][0], a01 = acc[s][pt][0][1], a02 = acc[s][pt][0][2], a03 = acc[s][pt][0][3];
      float a10 = acc[s][pt][1][0], a11 = acc[s][pt][1][1], a12 = acc[s][pt][1][2], a13 = acc[s][pt][1][3];
      float p00 = __shfl_xor(a00,8), p01 = __shfl_xor(a01,8);
      float p02 = __shfl_xor(a02,8), p03 = __shfl_xor(a03,8);
      float p10 = __shfl_xor(a10,8), p11 = __shfl_xor(a11,8);
      float p12 = __shfl_xor(a12,8), p13 = __shfl_xor(a13,8);
      float vi0 = hi8 ? p02 : a00;  float vf0 = hi8 ? a02 : p00;
      float vg0 = hi8 ? p12 : a10;  float vo0 = hi8 ? a12 : p10;
      float vi1 = hi8 ? p03 : a01;  float vf1 = hi8 ? a03 : p01;
      float vg1 = hi8 ? p13 : a11;  float vo1 = hi8 ? a13 : p11;
      float i0 = sigm2(vi0), f0 = sigm2(vf0), g0 = tanh2(vg0), o0 = sigm2(vo0);
      float i1 = sigm2(vi1), f1 = sigm2(vf1), g1 = tanh2(vg1), o1 = sigm2(vo1);
      c0[pt] = fmaf(f0, c0[pt], i0*g0);
      c1[pt] = fmaf(f1, c1[pt], i1*g1);
      float h0 = o0 * tanh_c(c0[pt]);
      float h1 = o1 * tanh_c(c1[pt]);
      int pth0 = pt*16 + lk*4 + hi8*2, pth1 = pth0 + 1;
      *(unsigned short*)(smem + wb + pth0*128 + ((dd*2) ^ ((pth0&7)<<4))) = cvh(h0);
      *(unsigned short*)(smem + wb + pth1*128 + ((dd*2) ^ ((pth1&7)<<4))) = cvh(h1);
    }
    __syncthreads();
  }
  // h_n now in AHB buf0 (bf16, swizzled)

  // ---- attention hidden: relu(h @ BA + ctxp) -> HIDB [32p][128] f32 overlays AF@0
  {
    const int pt = wid>>2, wg = wid&3;
    f32x4 acc2[2];
    #pragma unroll
    for (int nt=0;nt<2;++nt){
      float cv = ws[OFF_CTXP + wg*32 + nt*16 + ln];
      acc2[nt] = (f32x4){cv,cv,cv,cv};
    }
    #pragma unroll
    for (int kc=0;kc<2;++kc){
      bf16x8 ah = *(const bf16x8*)(smem + AHB + (pt*16 + ln)*128 + ((kc*64 + lk*16) ^ swA));
      bf16x8 bh0 = Bab[(unsigned)((kc*8 + wg*2+0)*64 + l)];
      bf16x8 bh1 = Bab[(unsigned)((kc*8 + wg*2+1)*64 + l)];
      acc2[0] = MFMA16(ah, bh0, acc2[0]);
      acc2[1] = MFMA16(ah, bh1, acc2[1]);
    }
    __syncthreads();   // AF reads done; safe to overlay
    #pragma unroll
    for (int nt=0;nt<2;++nt)
      #pragma unroll
      for (int r=0;r<4;++r)
        *(float*)(smem + (pt*16 + lk*4+r)*512 + (wg*32 + nt*16 + ln)*4) = fmaxf(acc2[nt][r], 0.f);
  }
  __syncthreads();
  // ---- score = hidden . att_W2 + b2 ; e = exp(score)
  {
    int p = t>>4, seg = t&15;
    float4 a0 = *(const float4*)(smem + p*512 + seg*32);
    float4 a1 = *(const float4*)(smem + p*512 + seg*32 + 16);
    float4 w0 = *(const float4*)(att_W2 + seg*8);
    float4 w1 = *(const float4*)(att_W2 + seg*8 + 4);
    float sc = a0.x*w0.x; sc = fmaf(a0.y,w0.y,sc); sc = fmaf(a0.z,w0.z,sc); sc = fmaf(a0.w,w0.w,sc);
    sc = fmaf(a1.x,w1.x,sc); sc = fmaf(a1.y,w1.y,sc); sc = fmaf(a1.z,w1.z,sc); sc = fmaf(a1.w,w1.w,sc);
    sc += __shfl_xor(sc,1); sc += __shfl_xor(sc,2); sc += __shfl_xor(sc,4); sc += __shfl_xor(sc,8);
    if (seg == 0){
      float e = __expf(sc + att_b2[0]);
      *(float*)(smem + ESO + p*4) = e;
      ws[OFF_E + p0 + p] = e;
    }
  }
  __syncthreads();
  // ---- partial sums: sum(e), sum(e*h)  (h as bf16 from AHB buf0)
  {
    int pg = t>>6, d = t&63;
    const float* es = (const float*)(smem + ESO);
    float a = 0.f;
    #pragma unroll
    for (int pi=0;pi<4;++pi){
      int p = pg*4 + pi;
      unsigned short hu = *(const unsigned short*)(smem + AHB + p*128 + ((d*2) ^ ((p&7)<<4)));
      a = fmaf(es[p], __uint_as_float((unsigned)hu << 16), a);
    }
    *(float*)(smem + PARTO + (pg*64+d)*4) = a;
  }
  __syncthreads();
  if (t < 64){
    const float* part = (const float*)(smem + PARTO);
    float a = 0.f;
    #pragma unroll
    for (int pg=0;pg<8;++pg) a += part[pg*64 + t];
    ws[OFF_PAGG + bid*64 + t] = a;
  }
  if (t < 32){
    float e2 = *(const float*)(smem + ESO + t*4);
    e2 += __shfl_xor(e2,1); e2 += __shfl_xor(e2,2);
    e2 += __shfl_xor(e2,4); e2 += __shfl_xor(e2,8); e2 += __shfl_xor(e2,16);
    if (t==0) ws[OFF_PE + bid] = e2;
  }
}

// ---------------------------------------------------------------- reduce stage A: 64 blocks
__global__ __launch_bounds__(256) void kredA(float* __restrict__ ws)
{
  const float* p_e   = ws + OFF_PE;
  const float* p_agg = ws + OFF_PAGG;
  __shared__ float red[256];
  const int b = blockIdx.x, t = threadIdx.x;
  const int s = b*4 + (t>>6), d = t&63;
  float a = 0.f;
  for (int row = s; row < NBLK; row += 256) a += p_agg[row*64 + d];
  ws[OFF_P2AGG + s*64 + d] = a;
  float pe = 0.f;
  {
    int i = b*49 + t;
    if (t < 49 && i < NBLK) pe = p_e[i];
  }
  pe += __shfl_xor(pe,1); pe += __shfl_xor(pe,2); pe += __shfl_xor(pe,4);
  pe += __shfl_xor(pe,8); pe += __shfl_xor(pe,16); pe += __shfl_xor(pe,32);
  if ((t&63)==0) red[t>>6] = pe;
  __syncthreads();
  if (t==0) ws[OFF_P2E + b] = red[0]+red[1]+red[2]+red[3];
}

// ---------------------------------------------------------------- merged reduce stage B + value head + weights: 392 blocks
__global__ __launch_bounds__(256) void kredBW(
    const float* __restrict__ val_W1, const float* __restrict__ val_b1,
    const float* __restrict__ val_W2, const float* __restrict__ val_b2,
    float* __restrict__ ws, float* __restrict__ d_out)
{
  __shared__ float Zsh;
  __shared__ float aggL[64];
  __shared__ float red[256];
  const int t = threadIdx.x, b = blockIdx.x;
  // local Z from 64 stage-2 partials (removes cross-kernel invZ dependency)
  if (t < 64){
    float pe = ws[OFF_P2E + t];
    pe += __shfl_xor(pe,1); pe += __shfl_xor(pe,2); pe += __shfl_xor(pe,4);
    pe += __shfl_xor(pe,8); pe += __shfl_xor(pe,16); pe += __shfl_xor(pe,32);
    if (t==0) Zsh = pe;
  }
  __syncthreads();
  const float invZ = 1.f / Zsh;
  if (b < 391){
    int p = b*256 + t;
    if (p < P_TOT) d_out[1+p] = ws[OFF_E + p] * invZ;
    return;
  }
  // value head (block 391)
  {
    int d = t&63, q = t>>6;
    float a = 0.f;
    #pragma unroll 4
    for (int s2=q; s2<256; s2+=4) a += ws[OFF_P2AGG + s2*64 + d];
    red[t] = a;
  }
  __syncthreads();
  if (t < 64) aggL[t] = (red[t] + red[64+t] + red[128+t] + red[192+t]) * invZ;
  __syncthreads();
  if (t < 32){
    float hv = val_b1[t];
    for (int k=0;k<64;++k) hv = fmaf(aggL[k], val_W1[t*64+k], hv);
    hv = fmaxf(hv, 0.f);
    float v = hv * val_W2[t];
    v += __shfl_xor(v,1); v += __shfl_xor(v,2); v += __shfl_xor(v,4);
    v += __shfl_xor(v,8); v += __shfl_xor(v,16);
    // q_value = value + (advantage - mean(advantage)) == value (advantage is [1])
    if (t==0) d_out[0] = (v + val_b2[0]) * ws[OFF_MISC+0];
  }
}

// ---------------------------------------------------------------- launch
extern "C" void kernel_launch(void* const* d_in, const int* in_sizes, int n_in,
                              void* d_out, int out_size, void* d_ws, size_t ws_size,
                              hipStream_t stream) {
  const int*   user_idx   = (const int*)  d_in[0];
  const int*   item_idx   = (const int*)  d_in[1];
  const int*   node_ids   = (const int*)  d_in[2];
  const int*   node_types = (const int*)  d_in[3];
  const int*   rel_idx    = (const int*)  d_in[4];
  const float* user_emb   = (const float*)d_in[5];
  const float* item_emb   = (const float*)d_in[6];
  const float* rel_emb    = (const float*)d_in[7];
  const float* ntype_emb  = (const float*)d_in[8];
  const float* W_ih       = (const float*)d_in[9];
  const float* W_hh       = (const float*)d_in[10];
  const float* b_ih       = (const float*)d_in[11];
  const float* b_hh       = (const float*)d_in[12];
  const float* att_W1     = (const float*)d_in[13];
  const float* att_b1     = (const float*)d_in[14];
  const float* att_W2     = (const float*)d_in[15];
  const float* att_b2     = (const float*)d_in[16];
  const float* val_W1     = (const float*)d_in[17];
  const float* val_b1     = (const float*)d_in[18];
  const float* val_W2     = (const float*)d_in[19];
  const float* val_b2     = (const float*)d_in[20];
  const float* saf_W1     = (const float*)d_in[25];
  const float* saf_b1     = (const float*)d_in[26];
  const float* saf_W2     = (const float*)d_in[27];
  const float* saf_b2     = (const float*)d_in[28];
  float* ws  = (float*)d_ws;
  float* out = (float*)d_out;

  const bool fast = (ws_size >= WS_FAST_BYTES);

  hipLaunchKernelGGL(kprepconv, dim3(fast ? (CONV_BLOCKS + PREP_BLOCKS) : PREP_BLOCKS), dim3(256), 0, stream,
                     user_idx, item_idx, user_emb, item_emb, rel_emb, ntype_emb,
                     W_ih, W_hh, b_ih, b_hh, att_W1, att_b1,
                     saf_W1, saf_b1, saf_W2, saf_b2, ws);
  if (fast){
    hipLaunchKernelGGL(klstm<1>, dim3(NBLK), dim3(512), 0, stream,
                       node_ids, node_types, rel_idx,
                       user_emb, item_emb, rel_emb, ntype_emb,
                       att_W2, att_b2, ws);
  } else {
    hipLaunchKernelGGL(klstm<0>, dim3(NBLK), dim3(512), 0, stream,
                       node_ids, node_types, rel_idx,
                       user_emb, item_emb, rel_emb, ntype_emb,
                       att_W2, att_b2, ws);
  }
  hipLaunchKernelGGL(kredA, dim3(64), dim3(256), 0, stream, ws);
  hipLaunchKernelGGL(kredBW, dim3(392), dim3(256), 0, stream,
                     val_W1, val_b1, val_W2, val_b2, ws, out);
}

// Round 14
// 112.631 us; speedup vs baseline: 1.1328x; 1.0147x over previous
//
#include <hip/hip_runtime.h>
#include <math.h>

#define P_TOT 100000
#define BM    32
#define NBLK  3125

// ws float offsets
#define OFF_BIH   0        // 96 frags (6kc x 8w x 2nt) x 1KB, GATE-PERMUTED cols, hi only, exp2-prescaled
#define OFF_BHH   24576    // 32 frags (2kc x 8w x 2nt), gate-permuted, hi only, exp2-prescaled
#define OFF_BA    32768    // 16 frags (2kc x 8ntg), standard cols, hi only (NOT scaled)
#define OFF_BSUM  36864    // 256 (natural order, exp2-prescaled)
#define OFF_CTXP  37120    // 128
#define OFF_MISC  37248    // [0]=safety, [1]=invZ
#define OFF_E     37264    // 100000
#define OFF_PE    137264   // 3125
#define OFF_PAGG  140392   // 3125*64
#define OFF_P2E   340392   // 64
#define OFF_P2AGG 340456   // 256*64
// hi-only bf16 embedding tables: [row][128B] = 32 f32-slots/row
#define OFF_TAB   356864
#define OFF_TU    (OFF_TAB)                 // 100000 rows
#define OFF_TI    (OFF_TAB + 3200000)       // 50000 rows
#define OFF_TR    (OFF_TAB + 4800000)       // 8 rows
#define OFF_TT    (OFF_TAB + 4800256)       // 2 rows
#define WS_FAST_BYTES ((size_t)(OFF_TAB + 4800320) * 4)

// klstm LDS (59520 B) — r11 layout
#define AHB   49152
#define ESO   57344
#define PARTO 57472
#define LDS_BYTES 59520

#define CONV_BLOCKS 4688   // ceil(150010*8/256)
#define PREP_BLOCKS 64

#define LOG2E  1.442695041f
#define LOG2E2 2.885390082f

typedef short bf16x8 __attribute__((ext_vector_type(8)));
typedef float f32x4  __attribute__((ext_vector_type(4)));

#define MFMA16(a,b,c) __builtin_amdgcn_mfma_f32_16x16x32_bf16((a),(b),(c),0,0,0)

__device__ __forceinline__ unsigned short cvh(float v){
  unsigned int u = __float_as_uint(v);
  return (unsigned short)((u + 0x7fffu + ((u>>16)&1u)) >> 16);
}
__device__ __forceinline__ float fexp2(float x){
#if __has_builtin(__builtin_amdgcn_exp2f)
  return __builtin_amdgcn_exp2f(x);
#else
  return exp2f(x);
#endif
}
__device__ __forceinline__ float frcp(float x){
#if __has_builtin(__builtin_amdgcn_rcpf)
  return __builtin_amdgcn_rcpf(x);
#else
  return 1.f/x;
#endif
}
__device__ __forceinline__ float sigm2(float zp){ return frcp(1.f + fexp2(-zp)); }

// fused LSTM gate update for one (path,dim):
//  vi,vf,vo pre-scaled by log2e; vg pre-scaled by 2*log2e; c in natural units.
//  i*g   = (eg-1) * rcp((eg+1)*(1+e^-i))
//  f     = rcp(1+e^-f)
//  c'    = f*c + i*g
//  h     = (ec-1) * rcp((ec+1)*(1+e^-o)),  ec = exp2(2*log2e*c')
__device__ __forceinline__ float lstm_h(float vi, float vf, float vg, float vo, float& c){
  float eg = fexp2(vg);
  float ei = fexp2(-vi);
  float ig = (eg - 1.f) * frcp((eg + 1.f) * (1.f + ei));
  float f  = frcp(1.f + fexp2(-vf));
  c = fmaf(f, c, ig);
  float ec = fexp2(c * LOG2E2);
  float eo = fexp2(-vo);
  return (ec - 1.f) * frcp((ec + 1.f) * (1.f + eo));
}

// ---------------------------------------------------------------- merged prep + table conversion
// last PREP_BLOCKS blocks do weight prep; preceding blocks (if any) do table conv
__global__ __launch_bounds__(256) void kprepconv(
    const int* __restrict__ user_idx, const int* __restrict__ item_idx,
    const float* __restrict__ user_emb, const float* __restrict__ item_emb,
    const float* __restrict__ relation_emb, const float* __restrict__ node_type_emb,
    const float* __restrict__ W_ih, const float* __restrict__ W_hh,
    const float* __restrict__ b_ih, const float* __restrict__ b_hh,
    const float* __restrict__ att_W1, const float* __restrict__ att_b1,
    const float* __restrict__ saf_W1, const float* __restrict__ saf_b1,
    const float* __restrict__ saf_W2, const float* __restrict__ saf_b2,
    float* __restrict__ ws)
{
  const int t = threadIdx.x;
  const int prep0 = (int)gridDim.x - PREP_BLOCKS;
  if ((int)blockIdx.x < prep0){
    // ---- table conversion (hi-only bf16)
    const int gid = blockIdx.x*256 + t;
    const int row = gid >> 3, seg = gid & 7;
    if (row >= 150010) return;
    const float* src; int dstoff;
    if (row < 100000){ src = user_emb + row*64;             dstoff = OFF_TU + row*32; }
    else if (row < 150000){ src = item_emb + (row-100000)*64; dstoff = OFF_TI + (row-100000)*32; }
    else if (row < 150008){ src = relation_emb + (row-150000)*64; dstoff = OFF_TR + (row-150000)*32; }
    else { src = node_type_emb + (row-150008)*64;           dstoff = OFF_TT + (row-150008)*32; }
    float4 v0 = ((const float4*)(src + seg*8))[0];
    float4 v1 = ((const float4*)(src + seg*8))[1];
    uint4 hq;
    hq.x = (unsigned)cvh(v0.x) | ((unsigned)cvh(v0.y)<<16);
    hq.y = (unsigned)cvh(v0.z) | ((unsigned)cvh(v0.w)<<16);
    hq.z = (unsigned)cvh(v1.x) | ((unsigned)cvh(v1.y)<<16);
    hq.w = (unsigned)cvh(v1.z) | ((unsigned)cvh(v1.w)<<16);
    *(uint4*)((char*)(ws + dstoff) + seg*16) = hq;
    return;
  }
  // ---- weight prep
  const int pb = (int)blockIdx.x - prep0;
  for (int fb = pb; fb < 144; fb += PREP_BLOCKS){
    const float* src; int base, rowlen, kc; bool perm; int w=0, nt=0, ntg=0;
    if (fb < 96){ kc = fb>>4; int rem = fb&15; w = rem>>1; nt = rem&1; perm = true;
                  base = OFF_BIH + fb*256; src = W_ih; rowlen = 192; }
    else if (fb < 128){ int f2 = fb-96; kc = f2>>4; int rem = f2&15; w = rem>>1; nt = rem&1; perm = true;
                  base = OFF_BHH + f2*256; src = W_hh; rowlen = 64; }
    else { int f3 = fb-128; kc = f3>>3; ntg = f3&7; perm = false;
                  base = OFF_BA + f3*256; src = att_W1; rowlen = 192; }
    unsigned short* dst = (unsigned short*)(ws + base);
    for (int e = t; e < 512; e += 256){
      int l = e>>3, j = e&7;
      int c = l&15;
      int n = perm ? (nt*2 + (c>>3))*64 + w*8 + (c&7)
                   : ntg*16 + c;
      int k = kc*32 + (l>>4)*8 + j;
      float v = src[n*rowlen + k];
      if (perm) v *= ((n>>6)==2 ? LOG2E2 : LOG2E);   // exp2 pre-scale per gate
      dst[e] = cvh(v);
    }
  }
  if (pb == 0){
    __shared__ float ctx[128];
    if (t < 256) ws[OFF_BSUM+t] = (b_ih[t] + b_hh[t]) * ((t>>6)==2 ? LOG2E2 : LOG2E);
    if (t < 64){
      ctx[t]    = user_emb[user_idx[0]*64 + t];
      ctx[64+t] = item_emb[item_idx[0]*64 + t];
    }
    __syncthreads();
    if (t < 128){
      float s = att_b1[t];
      for (int k=0;k<128;++k) s = fmaf(att_W1[t*192 + 64 + k], ctx[k], s);
      ws[OFF_CTXP + t] = s;
    }
    if (t < 32){
      float s = saf_b1[t];
      for (int k=0;k<128;++k) s = fmaf(saf_W1[t*128+k], ctx[k], s);
      s = fmaxf(s, 0.f);
      float v = s * saf_W2[t];
      v += __shfl_xor(v,1); v += __shfl_xor(v,2); v += __shfl_xor(v,4);
      v += __shfl_xor(v,8); v += __shfl_xor(v,16);
      if (t==0) ws[OFF_MISC+0] = 1.f/(1.f+expf(-(v + saf_b2[0])));
    }
  }
}

// ---------------------------------------------------------------- main: LSTM + attention (r11 structure, fused gates)
template<int PRE>
__global__ __launch_bounds__(512,4) void klstm(
    const int* __restrict__ node_ids, const int* __restrict__ node_types,
    const int* __restrict__ rel_idx,
    const float* __restrict__ user_emb, const float* __restrict__ item_emb,
    const float* __restrict__ relation_emb, const float* __restrict__ node_type_emb,
    const float* __restrict__ att_W2, const float* __restrict__ att_b2,
    float* __restrict__ ws)
{
  __shared__ __align__(16) unsigned char smem[LDS_BYTES];
  const int t   = threadIdx.x;
  const int l   = t & 63, wid = t >> 6;
  const int ln  = l & 15, lk = l >> 4;
  const int bid = blockIdx.x, p0 = bid*BM;
  const bf16x8* Bih = (const bf16x8*)(ws + OFF_BIH);
  const bf16x8* Bhh = (const bf16x8*)(ws + OFF_BHH);
  const bf16x8* Bab = (const bf16x8*)(ws + OFF_BA);
  const int swA = (ln&7)<<4;

  // ---- gather feats (4 steps x 3 srcs x 32 paths, hi only): 6 tasks/thread
  {
    const int c8 = t&7, rr = t>>3;
    #pragma unroll
    for (int i=0;i<6;++i){
      int task = rr + i*64;                 // [0,384)
      int src = task>>7, s = (task>>5)&3, p = task&31;
      int gi = (p0+p)*4 + s;
      int dsta = (s*32 + p)*384 + ((src*128 + c8*16) ^ ((p&7)<<4));
      if (PRE){
        const char* rp;
        if (src==0){ int nid = node_ids[gi];
                     rp = (const char*)(ws + (node_types[gi]==0 ? OFF_TU + nid*32 : OFF_TI + nid*32)); }
        else if (src==1){ rp = (const char*)(ws + OFF_TT + node_types[gi]*32); }
        else { rp = (const char*)(ws + OFF_TR + rel_idx[gi]*32); }
        *(uint4*)(smem + dsta) = *(const uint4*)(rp + c8*16);
      } else {
        const float* sp;
        if (src==0){ int nid = node_ids[gi]; sp = (node_types[gi]==0 ? user_emb : item_emb) + nid*64; }
        else if (src==1){ sp = node_type_emb + node_types[gi]*64; }
        else { sp = relation_emb + rel_idx[gi]*64; }
        float4 v0 = ((const float4*)sp)[c8*2];
        float4 v1 = ((const float4*)sp)[c8*2+1];
        uint4 hq;
        hq.x = (unsigned)cvh(v0.x) | ((unsigned)cvh(v0.y)<<16);
        hq.y = (unsigned)cvh(v0.z) | ((unsigned)cvh(v0.w)<<16);
        hq.z = (unsigned)cvh(v1.x) | ((unsigned)cvh(v1.y)<<16);
        hq.w = (unsigned)cvh(v1.z) | ((unsigned)cvh(v1.w)<<16);
        *(uint4*)(smem + dsta) = hq;
      }
    }
  }
  // ---- acc init with bias (permuted cols)
  f32x4 acc[4][2][2];     // [step][ptile][nt]
  {
    float bv0 = ws[OFF_BSUM + ((ln>>3))*64   + wid*8 + (ln&7)];
    float bv1 = ws[OFF_BSUM + (2+(ln>>3))*64 + wid*8 + (ln&7)];
    #pragma unroll
    for (int s=0;s<4;++s)
      #pragma unroll
      for (int pt=0;pt<2;++pt){
        acc[s][pt][0] = (f32x4){bv0,bv0,bv0,bv0};
        acc[s][pt][1] = (f32x4){bv1,bv1,bv1,bv1};
      }
  }
  __syncthreads();

  // ---- phase 1: Zfeat all 4 steps x 2 ptiles (K=192)
  #pragma unroll 2
  for (int kc=0;kc<6;++kc){
    bf16x8 bh0 = Bih[(unsigned)((kc*16 + wid*2+0)*64 + l)];
    bf16x8 bh1 = Bih[(unsigned)((kc*16 + wid*2+1)*64 + l)];
    #pragma unroll
    for (int s=0;s<4;++s)
      #pragma unroll
      for (int pt=0;pt<2;++pt){
        bf16x8 ah = *(const bf16x8*)(smem + (s*32 + pt*16 + ln)*384 + ((kc*64 + lk*16) ^ swA));
        acc[s][pt][0] = MFMA16(ah, bh0, acc[s][pt][0]);
        acc[s][pt][1] = MFMA16(ah, bh1, acc[s][pt][1]);
      }
  }

  // ---- phase 2: recurrence, gates from registers (shfl_xor 8), fused trans
  const int hi8 = ln>>3;
  const int dd  = wid*8 + (ln&7);
  float c0[2] = {0.f,0.f}, c1[2] = {0.f,0.f};
  #pragma unroll
  for (int s=0;s<4;++s){
    if (s > 0){
      const int rb = AHB + (s&1)*4096;
      #pragma unroll
      for (int kc=0;kc<2;++kc){
        bf16x8 bh0 = Bhh[(unsigned)((kc*16 + wid*2+0)*64 + l)];
        bf16x8 bh1 = Bhh[(unsigned)((kc*16 + wid*2+1)*64 + l)];
        #pragma unroll
        for (int pt=0;pt<2;++pt){
          bf16x8 ah = *(const bf16x8*)(smem + rb + (pt*16 + ln)*128 + ((kc*64 + lk*16) ^ swA));
          acc[s][pt][0] = MFMA16(ah, bh0, acc[s][pt][0]);
          acc[s][pt][1] = MFMA16(ah, bh1, acc[s][pt][1]);
        }
      }
    }
    const int wb = AHB + ((s&1)^1)*4096;
    #pragma unroll
    for (int pt=0;pt<2;++pt){
      float a00 = acc[s][pt][0][0], a01 = acc[s][pt][0][1], a02 = acc[s][pt][0][2], a03 = acc[s][pt][0][3];
      float a10 = acc[s][pt][1][0], a11 = acc[s][pt][1][1], a12 = acc[s][pt][1][2], a13 = acc[s][pt][1][3];
      float p00 = __shfl_xor(a00,8), p01 = __shfl_xor(a01,8);
      float p02 = __shfl_xor(a02,8), p03 = __shfl_xor(a03,8);
      float p10 = __shfl_xor(a10,8), p11 = __shfl_xor(a11,8);
      float p12 = __shfl_xor(a12,8), p13 = __shfl_xor(a13,8);
      float vi0 = hi8 ? p02 : a00;  float vf0 = hi8 ? a02 : p00;
      float vg0 = hi8 ? p12 : a10;  float vo0 = hi8 ? a12 : p10;
      float vi1 = hi8 ? p03 : a01;  float vf1 = hi8 ? a03 : p01;
      float vg1 = hi8 ? p13 : a11;  float vo1 = hi8 ? a13 : p11;
      float h0 = lstm_h(vi0, vf0, vg0, vo0, c0[pt]);
      float h1 = lstm_h(vi1, vf1, vg1, vo1, c1[pt]);
      int pth0 = pt*16 + lk*4 + hi8*2, pth1 = pth0 + 1;
      *(unsigned short*)(smem + wb + pth0*128 + ((dd*2) ^ ((pth0&7)<<4))) = cvh(h0);
      *(unsigned short*)(smem + wb + pth1*128 + ((dd*2) ^ ((pth1&7)<<4))) = cvh(h1);
    }
    __syncthreads();
  }
  // h_n now in AHB buf0 (bf16, swizzled)

  // ---- attention hidden: relu(h @ BA + ctxp) -> HIDB [32p][128] f32 overlays AF@0
  {
    const int pt = wid>>2, wg = wid&3;
    f32x4 acc2[2];
    #pragma unroll
    for (int nt=0;nt<2;++nt){
      float cv = ws[OFF_CTXP + wg*32 + nt*16 + ln];
      acc2[nt] = (f32x4){cv,cv,cv,cv};
    }
    #pragma unroll
    for (int kc=0;kc<2;++kc){
      bf16x8 ah = *(const bf16x8*)(smem + AHB + (pt*16 + ln)*128 + ((kc*64 + lk*16) ^ swA));
      bf16x8 bh0 = Bab[(unsigned)((kc*8 + wg*2+0)*64 + l)];
      bf16x8 bh1 = Bab[(unsigned)((kc*8 + wg*2+1)*64 + l)];
      acc2[0] = MFMA16(ah, bh0, acc2[0]);
      acc2[1] = MFMA16(ah, bh1, acc2[1]);
    }
    __syncthreads();   // AF reads done; safe to overlay
    #pragma unroll
    for (int nt=0;nt<2;++nt)
      #pragma unroll
      for (int r=0;r<4;++r)
        *(float*)(smem + (pt*16 + lk*4+r)*512 + (wg*32 + nt*16 + ln)*4) = fmaxf(acc2[nt][r], 0.f);
  }
  __syncthreads();
  // ---- score = hidden . att_W2 + b2 ; e = exp(score)
  {
    int p = t>>4, seg = t&15;
    float4 a0 = *(const float4*)(smem + p*512 + seg*32);
    float4 a1 = *(const float4*)(smem + p*512 + seg*32 + 16);
    float4 w0 = *(const float4*)(att_W2 + seg*8);
    float4 w1 = *(const float4*)(att_W2 + seg*8 + 4);
    float sc = a0.x*w0.x; sc = fmaf(a0.y,w0.y,sc); sc = fmaf(a0.z,w0.z,sc); sc = fmaf(a0.w,w0.w,sc);
    sc = fmaf(a1.x,w1.x,sc); sc = fmaf(a1.y,w1.y,sc); sc = fmaf(a1.z,w1.z,sc); sc = fmaf(a1.w,w1.w,sc);
    sc += __shfl_xor(sc,1); sc += __shfl_xor(sc,2); sc += __shfl_xor(sc,4); sc += __shfl_xor(sc,8);
    if (seg == 0){
      float e = __expf(sc + att_b2[0]);
      *(float*)(smem + ESO + p*4) = e;
      ws[OFF_E + p0 + p] = e;
    }
  }
  __syncthreads();
  // ---- partial sums: sum(e), sum(e*h)  (h as bf16 from AHB buf0)
  {
    int pg = t>>6, d = t&63;
    const float* es = (const float*)(smem + ESO);
    float a = 0.f;
    #pragma unroll
    for (int pi=0;pi<4;++pi){
      int p = pg*4 + pi;
      unsigned short hu = *(const unsigned short*)(smem + AHB + p*128 + ((d*2) ^ ((p&7)<<4)));
      a = fmaf(es[p], __uint_as_float((unsigned)hu << 16), a);
    }
    *(float*)(smem + PARTO + (pg*64+d)*4) = a;
  }
  __syncthreads();
  if (t < 64){
    const float* part = (const float*)(smem + PARTO);
    float a = 0.f;
    #pragma unroll
    for (int pg=0;pg<8;++pg) a += part[pg*64 + t];
    ws[OFF_PAGG + bid*64 + t] = a;
  }
  if (t < 32){
    float e2 = *(const float*)(smem + ESO + t*4);
    e2 += __shfl_xor(e2,1); e2 += __shfl_xor(e2,2);
    e2 += __shfl_xor(e2,4); e2 += __shfl_xor(e2,8); e2 += __shfl_xor(e2,16);
    if (t==0) ws[OFF_PE + bid] = e2;
  }
}

// ---------------------------------------------------------------- reduce stage A: 64 blocks
__global__ __launch_bounds__(256) void kredA(float* __restrict__ ws)
{
  const float* p_e   = ws + OFF_PE;
  const float* p_agg = ws + OFF_PAGG;
  __shared__ float red[256];
  const int b = blockIdx.x, t = threadIdx.x;
  const int s = b*4 + (t>>6), d = t&63;
  float a = 0.f;
  for (int row = s; row < NBLK; row += 256) a += p_agg[row*64 + d];
  ws[OFF_P2AGG + s*64 + d] = a;
  float pe = 0.f;
  {
    int i = b*49 + t;
    if (t < 49 && i < NBLK) pe = p_e[i];
  }
  pe += __shfl_xor(pe,1); pe += __shfl_xor(pe,2); pe += __shfl_xor(pe,4);
  pe += __shfl_xor(pe,8); pe += __shfl_xor(pe,16); pe += __shfl_xor(pe,32);
  if ((t&63)==0) red[t>>6] = pe;
  __syncthreads();
  if (t==0) ws[OFF_P2E + b] = red[0]+red[1]+red[2]+red[3];
}

// ---------------------------------------------------------------- merged reduce stage B + value head + weights: 392 blocks
__global__ __launch_bounds__(256) void kredBW(
    const float* __restrict__ val_W1, const float* __restrict__ val_b1,
    const float* __restrict__ val_W2, const float* __restrict__ val_b2,
    float* __restrict__ ws, float* __restrict__ d_out)
{
  __shared__ float Zsh;
  __shared__ float aggL[64];
  __shared__ float red[256];
  const int t = threadIdx.x, b = blockIdx.x;
  // local Z from 64 stage-2 partials (removes cross-kernel invZ dependency)
  if (t < 64){
    float pe = ws[OFF_P2E + t];
    pe += __shfl_xor(pe,1); pe += __shfl_xor(pe,2); pe += __shfl_xor(pe,4);
    pe += __shfl_xor(pe,8); pe += __shfl_xor(pe,16); pe += __shfl_xor(pe,32);
    if (t==0) Zsh = pe;
  }
  __syncthreads();
  const float invZ = 1.f / Zsh;
  if (b < 391){
    int p = b*256 + t;
    if (p < P_TOT) d_out[1+p] = ws[OFF_E + p] * invZ;
    return;
  }
  // value head (block 391)
  {
    int d = t&63, q = t>>6;
    float a = 0.f;
    #pragma unroll 4
    for (int s2=q; s2<256; s2+=4) a += ws[OFF_P2AGG + s2*64 + d];
    red[t] = a;
  }
  __syncthreads();
  if (t < 64) aggL[t] = (red[t] + red[64+t] + red[128+t] + red[192+t]) * invZ;
  __syncthreads();
  if (t < 32){
    float hv = val_b1[t];
    for (int k=0;k<64;++k) hv = fmaf(aggL[k], val_W1[t*64+k], hv);
    hv = fmaxf(hv, 0.f);
    float v = hv * val_W2[t];
    v += __shfl_xor(v,1); v += __shfl_xor(v,2); v += __shfl_xor(v,4);
    v += __shfl_xor(v,8); v += __shfl_xor(v,16);
    // q_value = value + (advantage - mean(advantage)) == value (advantage is [1])
    if (t==0) d_out[0] = (v + val_b2[0]) * ws[OFF_MISC+0];
  }
}

// ---------------------------------------------------------------- launch
extern "C" void kernel_launch(void* const* d_in, const int* in_sizes, int n_in,
                              void* d_out, int out_size, void* d_ws, size_t ws_size,
                              hipStream_t stream) {
  const int*   user_idx   = (const int*)  d_in[0];
  const int*   item_idx   = (const int*)  d_in[1];
  const int*   node_ids   = (const int*)  d_in[2];
  const int*   node_types = (const int*)  d_in[3];
  const int*   rel_idx    = (const int*)  d_in[4];
  const float* user_emb   = (const float*)d_in[5];
  const float* item_emb   = (const float*)d_in[6];
  const float* rel_emb    = (const float*)d_in[7];
  const float* ntype_emb  = (const float*)d_in[8];
  const float* W_ih       = (const float*)d_in[9];
  const float* W_hh       = (const float*)d_in[10];
  const float* b_ih       = (const float*)d_in[11];
  const float* b_hh       = (const float*)d_in[12];
  const float* att_W1     = (const float*)d_in[13];
  const float* att_b1     = (const float*)d_in[14];
  const float* att_W2     = (const float*)d_in[15];
  const float* att_b2     = (const float*)d_in[16];
  const float* val_W1     = (const float*)d_in[17];
  const float* val_b1     = (const float*)d_in[18];
  const float* val_W2     = (const float*)d_in[19];
  const float* val_b2     = (const float*)d_in[20];
  const float* saf_W1     = (const float*)d_in[25];
  const float* saf_b1     = (const float*)d_in[26];
  const float* saf_W2     = (const float*)d_in[27];
  const float* saf_b2     = (const float*)d_in[28];
  float* ws  = (float*)d_ws;
  float* out = (float*)d_out;

  const bool fast = (ws_size >= WS_FAST_BYTES);

  hipLaunchKernelGGL(kprepconv, dim3(fast ? (CONV_BLOCKS + PREP_BLOCKS) : PREP_BLOCKS), dim3(256), 0, stream,
                     user_idx, item_idx, user_emb, item_emb, rel_emb, ntype_emb,
                     W_ih, W_hh, b_ih, b_hh, att_W1, att_b1,
                     saf_W1, saf_b1, saf_W2, saf_b2, ws);
  if (fast){
    hipLaunchKernelGGL(klstm<1>, dim3(NBLK), dim3(512), 0, stream,
                       node_ids, node_types, rel_idx,
                       user_emb, item_emb, rel_emb, ntype_emb,
                       att_W2, att_b2, ws);
  } else {
    hipLaunchKernelGGL(klstm<0>, dim3(NBLK), dim3(512), 0, stream,
                       node_ids, node_types, rel_idx,
                       user_emb, item_emb, rel_emb, ntype_emb,
                       att_W2, att_b2, ws);
  }
  hipLaunchKernelGGL(kredA, dim3(64), dim3(256), 0, stream, ws);
  hipLaunchKernelGGL(kredBW, dim3(392), dim3(256), 0, stream,
                     val_W1, val_b1, val_W2, val_b2, ws, out);
}

// Round 15
// 109.620 us; speedup vs baseline: 1.1639x; 1.0275x over previous
//
#include <hip/hip_runtime.h>
#include <math.h>

#define P_TOT 100000
#define BM    32
#define NBLK  3125

// ws float offsets
#define OFF_BIH   0        // 96 frags (6kc x 8w x 2nt) x 1KB, GATE-PERMUTED cols, hi only, exp2-prescaled
#define OFF_BHH   24576    // 32 frags (2kc x 8w x 2nt), gate-permuted, hi only, exp2-prescaled
#define OFF_BA    32768    // 16 frags (2kc x 8ntg), standard cols, hi only (NOT scaled)
#define OFF_BSUM  36864    // 256 (natural order, exp2-prescaled)
#define OFF_CTXP  37120    // 128
#define OFF_MISC  37248    // [0]=safety, [1]=invZ
#define OFF_E     37264    // 100000
#define OFF_PE    137264   // 3125
#define OFF_PAGG  140392   // 3125*64
#define OFF_P2E   340392   // 64
#define OFF_P2AGG 340456   // 256*64

// klstm LDS (59520 B) — r11 layout
#define AHB   49152
#define ESO   57344
#define PARTO 57472
#define LDS_BYTES 59520

#define PREP_BLOCKS 64

#define LOG2E  1.442695041f
#define LOG2E2 2.885390082f

typedef short bf16x8 __attribute__((ext_vector_type(8)));
typedef float f32x4  __attribute__((ext_vector_type(4)));

#define MFMA16(a,b,c) __builtin_amdgcn_mfma_f32_16x16x32_bf16((a),(b),(c),0,0,0)

__device__ __forceinline__ unsigned short cvh(float v){
  unsigned int u = __float_as_uint(v);
  return (unsigned short)((u + 0x7fffu + ((u>>16)&1u)) >> 16);
}
// packed f32x2 -> bf16x2 (RNE), single instruction on gfx950
__device__ __forceinline__ unsigned cvt_pk(float lo, float hi){
  unsigned r;
  asm("v_cvt_pk_bf16_f32 %0, %1, %2" : "=v"(r) : "v"(lo), "v"(hi));
  return r;
}
__device__ __forceinline__ float fexp2(float x){
#if __has_builtin(__builtin_amdgcn_exp2f)
  return __builtin_amdgcn_exp2f(x);
#else
  return exp2f(x);
#endif
}
__device__ __forceinline__ float frcp(float x){
#if __has_builtin(__builtin_amdgcn_rcpf)
  return __builtin_amdgcn_rcpf(x);
#else
  return 1.f/x;
#endif
}
// fused LSTM gate update for one (path,dim):
//  vi,vf,vo pre-scaled by log2e; vg pre-scaled by 2*log2e; c in natural units.
__device__ __forceinline__ float lstm_h(float vi, float vf, float vg, float vo, float& c){
  float eg = fexp2(vg);
  float ei = fexp2(-vi);
  float ig = (eg - 1.f) * frcp((eg + 1.f) * (1.f + ei));
  float f  = frcp(1.f + fexp2(-vf));
  c = fmaf(f, c, ig);
  float ec = fexp2(c * LOG2E2);
  float eo = fexp2(-vo);
  return (ec - 1.f) * frcp((ec + 1.f) * (1.f + eo));
}

// ---------------------------------------------------------------- weight prep (64 blocks)
__global__ __launch_bounds__(256) void kprep(
    const int* __restrict__ user_idx, const int* __restrict__ item_idx,
    const float* __restrict__ user_emb, const float* __restrict__ item_emb,
    const float* __restrict__ W_ih, const float* __restrict__ W_hh,
    const float* __restrict__ b_ih, const float* __restrict__ b_hh,
    const float* __restrict__ att_W1, const float* __restrict__ att_b1,
    const float* __restrict__ saf_W1, const float* __restrict__ saf_b1,
    const float* __restrict__ saf_W2, const float* __restrict__ saf_b2,
    float* __restrict__ ws)
{
  const int t = threadIdx.x;
  const int pb = blockIdx.x;
  for (int fb = pb; fb < 144; fb += PREP_BLOCKS){
    const float* src; int base, rowlen, kc; bool perm; int w=0, nt=0, ntg=0;
    if (fb < 96){ kc = fb>>4; int rem = fb&15; w = rem>>1; nt = rem&1; perm = true;
                  base = OFF_BIH + fb*256; src = W_ih; rowlen = 192; }
    else if (fb < 128){ int f2 = fb-96; kc = f2>>4; int rem = f2&15; w = rem>>1; nt = rem&1; perm = true;
                  base = OFF_BHH + f2*256; src = W_hh; rowlen = 64; }
    else { int f3 = fb-128; kc = f3>>3; ntg = f3&7; perm = false;
                  base = OFF_BA + f3*256; src = att_W1; rowlen = 192; }
    unsigned short* dst = (unsigned short*)(ws + base);
    for (int e = t; e < 512; e += 256){
      int l = e>>3, j = e&7;
      int c = l&15;
      int n = perm ? (nt*2 + (c>>3))*64 + w*8 + (c&7)
                   : ntg*16 + c;
      int k = kc*32 + (l>>4)*8 + j;
      float v = src[n*rowlen + k];
      if (perm) v *= ((n>>6)==2 ? LOG2E2 : LOG2E);   // exp2 pre-scale per gate
      dst[e] = cvh(v);
    }
  }
  if (pb == 0){
    __shared__ float ctx[128];
    if (t < 256) ws[OFF_BSUM+t] = (b_ih[t] + b_hh[t]) * ((t>>6)==2 ? LOG2E2 : LOG2E);
    if (t < 64){
      ctx[t]    = user_emb[user_idx[0]*64 + t];
      ctx[64+t] = item_emb[item_idx[0]*64 + t];
    }
    __syncthreads();
    if (t < 128){
      float s = att_b1[t];
      for (int k=0;k<128;++k) s = fmaf(att_W1[t*192 + 64 + k], ctx[k], s);
      ws[OFF_CTXP + t] = s;
    }
    if (t < 32){
      float s = saf_b1[t];
      for (int k=0;k<128;++k) s = fmaf(saf_W1[t*128+k], ctx[k], s);
      s = fmaxf(s, 0.f);
      float v = s * saf_W2[t];
      v += __shfl_xor(v,1); v += __shfl_xor(v,2); v += __shfl_xor(v,4);
      v += __shfl_xor(v,8); v += __shfl_xor(v,16);
      if (t==0) ws[OFF_MISC+0] = 1.f/(1.f+expf(-(v + saf_b2[0])));
    }
  }
}

// ---------------------------------------------------------------- main: LSTM + attention
// gather reads f32 tables directly; conversion via v_cvt_pk_bf16_f32
__global__ __launch_bounds__(512,4) void klstm(
    const int* __restrict__ node_ids, const int* __restrict__ node_types,
    const int* __restrict__ rel_idx,
    const float* __restrict__ user_emb, const float* __restrict__ item_emb,
    const float* __restrict__ relation_emb, const float* __restrict__ node_type_emb,
    const float* __restrict__ att_W2, const float* __restrict__ att_b2,
    float* __restrict__ ws)
{
  __shared__ __align__(16) unsigned char smem[LDS_BYTES];
  const int t   = threadIdx.x;
  const int l   = t & 63, wid = t >> 6;
  const int ln  = l & 15, lk = l >> 4;
  const int bid = blockIdx.x, p0 = bid*BM;
  const bf16x8* Bih = (const bf16x8*)(ws + OFF_BIH);
  const bf16x8* Bhh = (const bf16x8*)(ws + OFF_BHH);
  const bf16x8* Bab = (const bf16x8*)(ws + OFF_BA);
  const int swA = (ln&7)<<4;

  // ---- gather feats (4 steps x 3 srcs x 32 paths): 6 tasks/thread, direct f32 + cvt_pk
  {
    const int c8 = t&7, rr = t>>3;
    #pragma unroll
    for (int i=0;i<6;++i){
      int task = rr + i*64;                 // [0,384)
      int src = task>>7, s = (task>>5)&3, p = task&31;
      int gi = (p0+p)*4 + s;
      int dsta = (s*32 + p)*384 + ((src*128 + c8*16) ^ ((p&7)<<4));
      const float* sp;
      if (src==0){ int nid = node_ids[gi]; sp = (node_types[gi]==0 ? user_emb : item_emb) + nid*64; }
      else if (src==1){ sp = node_type_emb + node_types[gi]*64; }
      else { sp = relation_emb + rel_idx[gi]*64; }
      float4 v0 = ((const float4*)sp)[c8*2];
      float4 v1 = ((const float4*)sp)[c8*2+1];
      uint4 hq;
      hq.x = cvt_pk(v0.x, v0.y);
      hq.y = cvt_pk(v0.z, v0.w);
      hq.z = cvt_pk(v1.x, v1.y);
      hq.w = cvt_pk(v1.z, v1.w);
      *(uint4*)(smem + dsta) = hq;
    }
  }
  // ---- acc init with bias (permuted cols)
  f32x4 acc[4][2][2];     // [step][ptile][nt]
  {
    float bv0 = ws[OFF_BSUM + ((ln>>3))*64   + wid*8 + (ln&7)];
    float bv1 = ws[OFF_BSUM + (2+(ln>>3))*64 + wid*8 + (ln&7)];
    #pragma unroll
    for (int s=0;s<4;++s)
      #pragma unroll
      for (int pt=0;pt<2;++pt){
        acc[s][pt][0] = (f32x4){bv0,bv0,bv0,bv0};
        acc[s][pt][1] = (f32x4){bv1,bv1,bv1,bv1};
      }
  }
  __syncthreads();

  // ---- phase 1: Zfeat all 4 steps x 2 ptiles (K=192)
  #pragma unroll 2
  for (int kc=0;kc<6;++kc){
    bf16x8 bh0 = Bih[(unsigned)((kc*16 + wid*2+0)*64 + l)];
    bf16x8 bh1 = Bih[(unsigned)((kc*16 + wid*2+1)*64 + l)];
    #pragma unroll
    for (int s=0;s<4;++s)
      #pragma unroll
      for (int pt=0;pt<2;++pt){
        bf16x8 ah = *(const bf16x8*)(smem + (s*32 + pt*16 + ln)*384 + ((kc*64 + lk*16) ^ swA));
        acc[s][pt][0] = MFMA16(ah, bh0, acc[s][pt][0]);
        acc[s][pt][1] = MFMA16(ah, bh1, acc[s][pt][1]);
      }
  }

  // ---- phase 2: recurrence, gates from registers (shfl_xor 8), fused trans
  const int hi8 = ln>>3;
  const int dd  = wid*8 + (ln&7);
  float c0[2] = {0.f,0.f}, c1[2] = {0.f,0.f};
  #pragma unroll
  for (int s=0;s<4;++s){
    if (s > 0){
      const int rb = AHB + (s&1)*4096;
      #pragma unroll
      for (int kc=0;kc<2;++kc){
        bf16x8 bh0 = Bhh[(unsigned)((kc*16 + wid*2+0)*64 + l)];
        bf16x8 bh1 = Bhh[(unsigned)((kc*16 + wid*2+1)*64 + l)];
        #pragma unroll
        for (int pt=0;pt<2;++pt){
          bf16x8 ah = *(const bf16x8*)(smem + rb + (pt*16 + ln)*128 + ((kc*64 + lk*16) ^ swA));
          acc[s][pt][0] = MFMA16(ah, bh0, acc[s][pt][0]);
          acc[s][pt][1] = MFMA16(ah, bh1, acc[s][pt][1]);
        }
      }
    }
    const int wb = AHB + ((s&1)^1)*4096;
    #pragma unroll
    for (int pt=0;pt<2;++pt){
      float a00 = acc[s][pt][0][0], a01 = acc[s][pt][0][1], a02 = acc[s][pt][0][2], a03 = acc[s][pt][0][3];
      float a10 = acc[s][pt][1][0], a11 = acc[s][pt][1][1], a12 = acc[s][pt][1][2], a13 = acc[s][pt][1][3];
      float p00 = __shfl_xor(a00,8), p01 = __shfl_xor(a01,8);
      float p02 = __shfl_xor(a02,8), p03 = __shfl_xor(a03,8);
      float p10 = __shfl_xor(a10,8), p11 = __shfl_xor(a11,8);
      float p12 = __shfl_xor(a12,8), p13 = __shfl_xor(a13,8);
      float vi0 = hi8 ? p02 : a00;  float vf0 = hi8 ? a02 : p00;
      float vg0 = hi8 ? p12 : a10;  float vo0 = hi8 ? a12 : p10;
      float vi1 = hi8 ? p03 : a01;  float vf1 = hi8 ? a03 : p01;
      float vg1 = hi8 ? p13 : a11;  float vo1 = hi8 ? a13 : p11;
      float h0 = lstm_h(vi0, vf0, vg0, vo0, c0[pt]);
      float h1 = lstm_h(vi1, vf1, vg1, vo1, c1[pt]);
      int pth0 = pt*16 + lk*4 + hi8*2, pth1 = pth0 + 1;
      *(unsigned short*)(smem + wb + pth0*128 + ((dd*2) ^ ((pth0&7)<<4))) = cvh(h0);
      *(unsigned short*)(smem + wb + pth1*128 + ((dd*2) ^ ((pth1&7)<<4))) = cvh(h1);
    }
    __syncthreads();
  }
  // h_n now in AHB buf0 (bf16, swizzled)

  // ---- attention hidden: relu(h @ BA + ctxp) -> HIDB [32p][128] f32 overlays AF@0
  {
    const int pt = wid>>2, wg = wid&3;
    f32x4 acc2[2];
    #pragma unroll
    for (int nt=0;nt<2;++nt){
      float cv = ws[OFF_CTXP + wg*32 + nt*16 + ln];
      acc2[nt] = (f32x4){cv,cv,cv,cv};
    }
    #pragma unroll
    for (int kc=0;kc<2;++kc){
      bf16x8 ah = *(const bf16x8*)(smem + AHB + (pt*16 + ln)*128 + ((kc*64 + lk*16) ^ swA));
      bf16x8 bh0 = Bab[(unsigned)((kc*8 + wg*2+0)*64 + l)];
      bf16x8 bh1 = Bab[(unsigned)((kc*8 + wg*2+1)*64 + l)];
      acc2[0] = MFMA16(ah, bh0, acc2[0]);
      acc2[1] = MFMA16(ah, bh1, acc2[1]);
    }
    __syncthreads();   // AF reads done; safe to overlay
    #pragma unroll
    for (int nt=0;nt<2;++nt)
      #pragma unroll
      for (int r=0;r<4;++r)
        *(float*)(smem + (pt*16 + lk*4+r)*512 + (wg*32 + nt*16 + ln)*4) = fmaxf(acc2[nt][r], 0.f);
  }
  __syncthreads();
  // ---- score = hidden . att_W2 + b2 ; e = exp(score)
  {
    int p = t>>4, seg = t&15;
    float4 a0 = *(const float4*)(smem + p*512 + seg*32);
    float4 a1 = *(const float4*)(smem + p*512 + seg*32 + 16);
    float4 w0 = *(const float4*)(att_W2 + seg*8);
    float4 w1 = *(const float4*)(att_W2 + seg*8 + 4);
    float sc = a0.x*w0.x; sc = fmaf(a0.y,w0.y,sc); sc = fmaf(a0.z,w0.z,sc); sc = fmaf(a0.w,w0.w,sc);
    sc = fmaf(a1.x,w1.x,sc); sc = fmaf(a1.y,w1.y,sc); sc = fmaf(a1.z,w1.z,sc); sc = fmaf(a1.w,w1.w,sc);
    sc += __shfl_xor(sc,1); sc += __shfl_xor(sc,2); sc += __shfl_xor(sc,4); sc += __shfl_xor(sc,8);
    if (seg == 0){
      float e = __expf(sc + att_b2[0]);
      *(float*)(smem + ESO + p*4) = e;
      ws[OFF_E + p0 + p] = e;
    }
  }
  __syncthreads();
  // ---- partial sums: sum(e), sum(e*h)  (h as bf16 from AHB buf0)
  {
    int pg = t>>6, d = t&63;
    const float* es = (const float*)(smem + ESO);
    float a = 0.f;
    #pragma unroll
    for (int pi=0;pi<4;++pi){
      int p = pg*4 + pi;
      unsigned short hu = *(const unsigned short*)(smem + AHB + p*128 + ((d*2) ^ ((p&7)<<4)));
      a = fmaf(es[p], __uint_as_float((unsigned)hu << 16), a);
    }
    *(float*)(smem + PARTO + (pg*64+d)*4) = a;
  }
  __syncthreads();
  if (t < 64){
    const float* part = (const float*)(smem + PARTO);
    float a = 0.f;
    #pragma unroll
    for (int pg=0;pg<8;++pg) a += part[pg*64 + t];
    ws[OFF_PAGG + bid*64 + t] = a;
  }
  if (t < 32){
    float e2 = *(const float*)(smem + ESO + t*4);
    e2 += __shfl_xor(e2,1); e2 += __shfl_xor(e2,2);
    e2 += __shfl_xor(e2,4); e2 += __shfl_xor(e2,8); e2 += __shfl_xor(e2,16);
    if (t==0) ws[OFF_PE + bid] = e2;
  }
}

// ---------------------------------------------------------------- reduce stage A: 64 blocks
__global__ __launch_bounds__(256) void kredA(float* __restrict__ ws)
{
  const float* p_e   = ws + OFF_PE;
  const float* p_agg = ws + OFF_PAGG;
  __shared__ float red[256];
  const int b = blockIdx.x, t = threadIdx.x;
  const int s = b*4 + (t>>6), d = t&63;
  float a = 0.f;
  for (int row = s; row < NBLK; row += 256) a += p_agg[row*64 + d];
  ws[OFF_P2AGG + s*64 + d] = a;
  float pe = 0.f;
  {
    int i = b*49 + t;
    if (t < 49 && i < NBLK) pe = p_e[i];
  }
  pe += __shfl_xor(pe,1); pe += __shfl_xor(pe,2); pe += __shfl_xor(pe,4);
  pe += __shfl_xor(pe,8); pe += __shfl_xor(pe,16); pe += __shfl_xor(pe,32);
  if ((t&63)==0) red[t>>6] = pe;
  __syncthreads();
  if (t==0) ws[OFF_P2E + b] = red[0]+red[1]+red[2]+red[3];
}

// ---------------------------------------------------------------- merged reduce stage B + value head + weights: 392 blocks
__global__ __launch_bounds__(256) void kredBW(
    const float* __restrict__ val_W1, const float* __restrict__ val_b1,
    const float* __restrict__ val_W2, const float* __restrict__ val_b2,
    float* __restrict__ ws, float* __restrict__ d_out)
{
  __shared__ float Zsh;
  __shared__ float aggL[64];
  __shared__ float red[256];
  const int t = threadIdx.x, b = blockIdx.x;
  if (t < 64){
    float pe = ws[OFF_P2E + t];
    pe += __shfl_xor(pe,1); pe += __shfl_xor(pe,2); pe += __shfl_xor(pe,4);
    pe += __shfl_xor(pe,8); pe += __shfl_xor(pe,16); pe += __shfl_xor(pe,32);
    if (t==0) Zsh = pe;
  }
  __syncthreads();
  const float invZ = 1.f / Zsh;
  if (b < 391){
    int p = b*256 + t;
    if (p < P_TOT) d_out[1+p] = ws[OFF_E + p] * invZ;
    return;
  }
  // value head (block 391)
  {
    int d = t&63, q = t>>6;
    float a = 0.f;
    #pragma unroll 4
    for (int s2=q; s2<256; s2+=4) a += ws[OFF_P2AGG + s2*64 + d];
    red[t] = a;
  }
  __syncthreads();
  if (t < 64) aggL[t] = (red[t] + red[64+t] + red[128+t] + red[192+t]) * invZ;
  __syncthreads();
  if (t < 32){
    float hv = val_b1[t];
    for (int k=0;k<64;++k) hv = fmaf(aggL[k], val_W1[t*64+k], hv);
    hv = fmaxf(hv, 0.f);
    float v = hv * val_W2[t];
    v += __shfl_xor(v,1); v += __shfl_xor(v,2); v += __shfl_xor(v,4);
    v += __shfl_xor(v,8); v += __shfl_xor(v,16);
    // q_value = value + (advantage - mean(advantage)) == value (advantage is [1])
    if (t==0) d_out[0] = (v + val_b2[0]) * ws[OFF_MISC+0];
  }
}

// ---------------------------------------------------------------- launch
extern "C" void kernel_launch(void* const* d_in, const int* in_sizes, int n_in,
                              void* d_out, int out_size, void* d_ws, size_t ws_size,
                              hipStream_t stream) {
  const int*   user_idx   = (const int*)  d_in[0];
  const int*   item_idx   = (const int*)  d_in[1];
  const int*   node_ids   = (const int*)  d_in[2];
  const int*   node_types = (const int*)  d_in[3];
  const int*   rel_idx    = (const int*)  d_in[4];
  const float* user_emb   = (const float*)d_in[5];
  const float* item_emb   = (const float*)d_in[6];
  const float* rel_emb    = (const float*)d_in[7];
  const float* ntype_emb  = (const float*)d_in[8];
  const float* W_ih       = (const float*)d_in[9];
  const float* W_hh       = (const float*)d_in[10];
  const float* b_ih       = (const float*)d_in[11];
  const float* b_hh       = (const float*)d_in[12];
  const float* att_W1     = (const float*)d_in[13];
  const float* att_b1     = (const float*)d_in[14];
  const float* att_W2     = (const float*)d_in[15];
  const float* att_b2     = (const float*)d_in[16];
  const float* val_W1     = (const float*)d_in[17];
  const float* val_b1     = (const float*)d_in[18];
  const float* val_W2     = (const float*)d_in[19];
  const float* val_b2     = (const float*)d_in[20];
  const float* saf_W1     = (const float*)d_in[25];
  const float* saf_b1     = (const float*)d_in[26];
  const float* saf_W2     = (const float*)d_in[27];
  const float* saf_b2     = (const float*)d_in[28];
  float* ws  = (float*)d_ws;
  float* out = (float*)d_out;

  hipLaunchKernelGGL(kprep, dim3(PREP_BLOCKS), dim3(256), 0, stream,
                     user_idx, item_idx, user_emb, item_emb,
                     W_ih, W_hh, b_ih, b_hh, att_W1, att_b1,
                     saf_W1, saf_b1, saf_W2, saf_b2, ws);
  hipLaunchKernelGGL(klstm, dim3(NBLK), dim3(512), 0, stream,
                     node_ids, node_types, rel_idx,
                     user_emb, item_emb, rel_emb, ntype_emb,
                     att_W2, att_b2, ws);
  hipLaunchKernelGGL(kredA, dim3(64), dim3(256), 0, stream, ws);
  hipLaunchKernelGGL(kredBW, dim3(392), dim3(256), 0, stream,
                     val_W1, val_b1, val_W2, val_b2, ws, out);
}